// Round 3
// baseline (777.851 us; speedup 1.0000x reference)
//
#include <hip/hip_runtime.h>
#include <math.h>

#define BLK 64
#define EPB 16            // elements per block (one wave)
#define NF 32

typedef __attribute__((ext_vector_type(8))) short s16x8;  // 8 bf16 = 4 VGPRs
typedef __attribute__((ext_vector_type(4))) float f32x4;

__device__ __forceinline__ float sigm(float x) {
    return __fdividef(1.0f, 1.0f + __expf(-x));
}
__device__ __forceinline__ float tanhft(float x) {
    float a = fabsf(x);
    float e = __expf(-2.0f * a);
    float t = __fdividef(1.0f - e, 1.0f + e);
    return copysignf(t, x);
}

__device__ __forceinline__ unsigned short bf16h(float x) {
    unsigned u = __float_as_uint(x);
    return (unsigned short)((u + 0x7FFFu + ((u >> 16) & 1u)) >> 16);
}
__device__ __forceinline__ float bf16tof(unsigned short h) {
    return __uint_as_float(((unsigned)h) << 16);
}
// split fp32 into hi+lo bf16 (~17-bit effective mantissa)
__device__ __forceinline__ void bsplit(float x, short& hi, short& lo) {
    unsigned short h = bf16h(x);
    hi = (short)h;
    lo = (short)bf16h(x - bf16tof(h));
}

// P = F P F^T for the constant-accel F (dt=0.2), in place
__device__ __forceinline__ void fpft(float (&P)[6][6]) {
    const float dt = 0.2f, hd = 0.02f;
    #pragma unroll
    for (int j = 0; j < 6; ++j) {
        float a0 = P[0][j] + dt * P[1][j] + hd * P[2][j];
        float a1 = P[1][j] + dt * P[2][j];
        float a3 = P[3][j] + dt * P[4][j] + hd * P[5][j];
        float a4 = P[4][j] + dt * P[5][j];
        P[0][j] = a0; P[1][j] = a1; P[3][j] = a3; P[4][j] = a4;
    }
    #pragma unroll
    for (int i = 0; i < 6; ++i) {
        float a0 = P[i][0] + dt * P[i][1] + hd * P[i][2];
        float a1 = P[i][1] + dt * P[i][2];
        float a3 = P[i][3] + dt * P[i][4] + hd * P[i][5];
        float a4 = P[i][4] + dt * P[i][5];
        P[i][0] = a0; P[i][1] = a1; P[i][3] = a3; P[i][4] = a4;
    }
}

#define GSTRIDE 21   // LDS gate buffer row stride (floats): <=2-way bank conflicts

__global__ __launch_bounds__(BLK, 2)
void kalman_lstm(const float* __restrict__ hist,
                 const float* __restrict__ psx, const float* __restrict__ psy,
                 const float* __restrict__ vsx, const float* __restrict__ vsy,
                 const float* __restrict__ asx, const float* __restrict__ asy,
                 const float* __restrict__ jerk, const float* __restrict__ coefG,
                 const float* __restrict__ GRv,
                 const float* __restrict__ cfW, const float* __restrict__ cfb,
                 const float* __restrict__ Wih, const float* __restrict__ Whh,
                 const float* __restrict__ bih, const float* __restrict__ bhh,
                 const float* __restrict__ coW, const float* __restrict__ cob,
                 float* __restrict__ out, int B, int Thist, int len_pred)
{
    __shared__ float gbuf[128 * GSTRIDE];   // [gate 0..127][elem 0..15], stride 21

    const int lane = threadIdx.x;
    const int e = lane & 15;        // element slot within block
    const int s = lane >> 4;        // quad: k-slice / feature-slice owner
    const int b = blockIdx.x * EPB + e;

    const float dt = 0.2f;
    const float hd = 0.02f;
    const float g0 = dt * dt * dt / 6.0f;
    const float g1 = 0.02f;
    const float g2 = dt;

    // ---- uniform precompute (lean: qa/qb recomputed per history step) ----
    float gr0 = GRv[0], gr1 = GRv[1];
    float R00 = gr0 * gr0, R01 = gr0 * gr1, R11 = gr1 * gr1;
    float ga0 = g0 * tanhf(coefG[0]);
    float ga1 = g1 * tanhf(coefG[1]);
    float ga2 = g2 * tanhf(coefG[2]);
    float gb3 = g0 * tanhf(coefG[3]);
    float gb4 = g1 * tanhf(coefG[4]);
    float gb5 = g2 * tanhf(coefG[5]);
    float j0 = jerk[0], j1 = jerk[1];

    // ---- LSTM weights once into register B-fragments (hi/lo bf16 split) ----
    s16x8 wih_h[8], wih_l[8], whh_h[8], whh_l[8];
    #pragma unroll
    for (int nt = 0; nt < 8; ++nt) {
        int row = nt * 16 + e;
        int base = row * NF + s * 8;
        #pragma unroll
        for (int j = 0; j < 8; ++j) {
            short hi, lo;
            bsplit(Wih[base + j], hi, lo);
            wih_h[nt][j] = hi; wih_l[nt][j] = lo;
            bsplit(Whh[base + j], hi, lo);
            whh_h[nt][j] = hi; whh_l[nt][j] = lo;
        }
    }
    float bias8[8];
    #pragma unroll
    for (int nt = 0; nt < 8; ++nt) {
        int g = nt * 16 + e;
        bias8[nt] = bih[g] + bhh[g];
    }

    // ---- Kalman init (replicated across the 4 lanes of each element) ----
    const float2* hist2 = (const float2*)hist;
    float2 z0 = hist2[b];
    float2 z1 = hist2[B + b];
    float X0 = z0.x, X1 = (z1.x - z0.x) / dt, X2 = 0.0f;
    float X3 = (z1.y - z0.y) / dt, X4 = 0.0f, X5 = 0.0f;  // ref overwrites slot 3

    float P[6][6];
    #pragma unroll
    for (int i = 0; i < 6; ++i)
        #pragma unroll
        for (int j = 0; j < 6; ++j) P[i][j] = 0.0f;
    { float v;
      v = psx[0]; P[0][0] = v * v;
      v = vsx[0]; P[1][1] = v * v;
      v = asx[0]; P[2][2] = v * v;
      v = psy[0]; P[3][3] = v * v;
      v = vsy[0]; P[4][4] = v * v;
      v = asy[0]; P[5][5] = v * v; }

    float creg[8];
    #pragma unroll
    for (int j = 0; j < 8; ++j) creg[j] = 0.0f;
    s16x8 ah_h = (s16x8)0, ah_l = (s16x8)0;   // h as A-fragment

    const int total = Thist + len_pred;
    for (int t = 0; t < total; ++t) {
        // ---- feat slice: f = 8s+jj, from current X ----
        s16x8 af_h, af_l;
        #pragma unroll
        for (int jj = 0; jj < 8; ++jj) {
            int f = 8 * s + jj;
            float acc = cfb[f]
                + cfW[f * 6 + 0] * X0 + cfW[f * 6 + 1] * X1 + cfW[f * 6 + 2] * X2
                + cfW[f * 6 + 3] * X3 + cfW[f * 6 + 4] * X4 + cfW[f * 6 + 5] * X5;
            float fv = tanhft(acc);
            short hi, lo; bsplit(fv, hi, lo);
            af_h[jj] = hi; af_l[jj] = lo;
        }

        __syncthreads();   // WAR on gbuf

        // ---- gates = [feat|h] @ W^T via MFMA (hi/lo split) ----
        #pragma unroll
        for (int nt = 0; nt < 8; ++nt) {
            f32x4 acc = {bias8[nt], bias8[nt], bias8[nt], bias8[nt]};
            acc = __builtin_amdgcn_mfma_f32_16x16x32_bf16(af_h, wih_h[nt], acc, 0, 0, 0);
            acc = __builtin_amdgcn_mfma_f32_16x16x32_bf16(af_l, wih_h[nt], acc, 0, 0, 0);
            acc = __builtin_amdgcn_mfma_f32_16x16x32_bf16(af_h, wih_l[nt], acc, 0, 0, 0);
            acc = __builtin_amdgcn_mfma_f32_16x16x32_bf16(ah_h, whh_h[nt], acc, 0, 0, 0);
            acc = __builtin_amdgcn_mfma_f32_16x16x32_bf16(ah_l, whh_h[nt], acc, 0, 0, 0);
            acc = __builtin_amdgcn_mfma_f32_16x16x32_bf16(ah_h, whh_l[nt], acc, 0, 0, 0);
            int wbase = (nt * 16 + e) * GSTRIDE + s * 4;
            gbuf[wbase + 0] = acc[0];
            gbuf[wbase + 1] = acc[1];
            gbuf[wbase + 2] = acc[2];
            gbuf[wbase + 3] = acc[3];
        }

        __syncthreads();   // RAW on gbuf

        // ---- combine: lane (e,s) handles features [8s,8s+8) of element e ----
        #pragma unroll
        for (int jj = 0; jj < 8; ++jj) {
            int f = 8 * s + jj;
            float gi = gbuf[(f)      * GSTRIDE + e];
            float gf = gbuf[(32 + f) * GSTRIDE + e];
            float gg = gbuf[(64 + f) * GSTRIDE + e];
            float go = gbuf[(96 + f) * GSTRIDE + e];
            float cn = sigm(gf) * creg[jj] + sigm(gi) * tanhft(gg);
            creg[jj] = cn;
            float hn = sigm(go) * tanhft(cn);
            short hi, lo; bsplit(hn, hi, lo);
            ah_h[jj] = hi; ah_l[jj] = lo;
        }

        if (t < Thist) {
            // ---------- history step: predict + measurement update ----------
            float2 z = hist2[(size_t)(t + 1) * B + b];
            X0 = X0 + dt * X1 + hd * X2;  X1 = X1 + dt * X2;
            X3 = X3 + dt * X4 + hd * X5;  X4 = X4 + dt * X5;
            fpft(P);
            {   // Q_hist = blockdiag(qa qa^T, qb qb^T), qa = ga*j0, qb = gb*j1
                float qa[3] = {ga0 * j0, ga1 * j0, ga2 * j0};
                float qb[3] = {gb3 * j1, gb4 * j1, gb5 * j1};
                #pragma unroll
                for (int i = 0; i < 3; ++i)
                    #pragma unroll
                    for (int j = 0; j < 3; ++j) {
                        P[i][j]         += qa[i] * qa[j];
                        P[3 + i][3 + j] += qb[i] * qb[j];
                    }
            }
            float y0 = z.x - X0, y1 = z.y - X3;
            float S00 = P[0][0] + R00;
            float S01 = P[0][3] + R01;           // = S10 (P symmetric)
            float S11 = P[3][3] + R11;
            float idet = 1.0f / (S00 * S11 - S01 * S01);
            float i00 =  S11 * idet, i01 = -S01 * idet, i11 = S00 * idet;
            float K0[6], K1[6];
            #pragma unroll
            for (int i = 0; i < 6; ++i) {
                K0[i] = P[i][0] * i00 + P[i][3] * i01;
                K1[i] = P[i][0] * i01 + P[i][3] * i11;
            }
            X0 += K0[0] * y0 + K1[0] * y1;
            X1 += K0[1] * y0 + K1[1] * y1;
            X2 += K0[2] * y0 + K1[2] * y1;
            X3 += K0[3] * y0 + K1[3] * y1;
            X4 += K0[4] * y0 + K1[4] * y1;
            X5 += K0[5] * y0 + K1[5] * y1;
            // P' = (I-KH)P  (== Joseph exactly for optimal K), in place:
            // columns != {0,3} first (they read cols 0,3), then cols 0,3 per-row.
            #pragma unroll
            for (int i = 0; i < 6; ++i) {
                P[i][1] -= K0[1] * P[i][0] + K1[1] * P[i][3];
                P[i][2] -= K0[2] * P[i][0] + K1[2] * P[i][3];
                P[i][4] -= K0[4] * P[i][0] + K1[4] * P[i][3];
                P[i][5] -= K0[5] * P[i][0] + K1[5] * P[i][3];
                float t0 = P[i][0] - (K0[0] * P[i][0] + K1[0] * P[i][3]);
                float t3 = P[i][3] - (K0[3] * P[i][0] + K1[3] * P[i][3]);
                P[i][0] = t0; P[i][3] = t3;
            }
        } else {
            // ---------- prediction step ----------
            // command = coW @ h + cob; h reconstructed from ah hi/lo
            float c0 = 0.0f, c1 = 0.0f, c2 = 0.0f, c3 = 0.0f;
            #pragma unroll
            for (int jj = 0; jj < 8; ++jj) {
                int f = 8 * s + jj;
                float hk = bf16tof((unsigned short)ah_h[jj])
                         + bf16tof((unsigned short)ah_l[jj]);
                c0 += coW[0 * NF + f] * hk;
                c1 += coW[1 * NF + f] * hk;
                c2 += coW[2 * NF + f] * hk;
                c3 += coW[3 * NF + f] * hk;
            }
            c0 += __shfl_xor(c0, 16, 64); c0 += __shfl_xor(c0, 32, 64);
            c1 += __shfl_xor(c1, 16, 64); c1 += __shfl_xor(c1, 32, 64);
            c2 += __shfl_xor(c2, 16, 64); c2 += __shfl_xor(c2, 32, 64);
            c3 += __shfl_xor(c3, 16, 64); c3 += __shfl_xor(c3, 32, 64);
            float cmd0 = c0 + cob[0], cmd1 = c1 + cob[1];
            float cmd2 = c2 + cob[2], cmd3 = c3 + cob[3];

            X0 = X0 + dt * X1 + hd * X2 + g0 * cmd0;
            X1 = X1 + dt * X2 + g1 * cmd0;
            X2 = X2 + g2 * cmd0;
            X3 = X3 + dt * X4 + hd * X5 + g0 * cmd1;
            X4 = X4 + dt * X5 + g1 * cmd1;
            X5 = X5 + g2 * cmd1;
            float Gs[6] = {ga0 * cmd2, ga1 * cmd2, ga2 * cmd2,
                           gb3 * cmd3, gb4 * cmd3, gb5 * cmd3};
            fpft(P);
            #pragma unroll
            for (int i = 0; i < 6; ++i)
                #pragma unroll
                for (int j = 0; j < 6; ++j)
                    P[i][j] += Gs[i] * Gs[j];

            int tp = t - Thist;
            float sx = sqrtf(P[0][0]), sy = sqrtf(P[3][3]);
            float rho = (P[0][3] + P[3][0]) / (2.0f * sx * sy);
            if (s == 0) {
                size_t o = ((size_t)tp * B + b) * 5u;
                out[o + 0] = X0;
                out[o + 1] = X3;
                out[o + 2] = sx;
                out[o + 3] = sy;
                out[o + 4] = rho;
            }
        }
    }
}

extern "C" void kernel_launch(void* const* d_in, const int* in_sizes, int n_in,
                              void* d_out, int out_size, void* d_ws, size_t ws_size,
                              hipStream_t stream) {
    const int T = 16;
    const int B = in_sizes[0] / (2 * T);      // 32768
    const int len_pred = out_size / (5 * B);  // 25
    const int grid = (B + EPB - 1) / EPB;     // one wave per 16 elements
    kalman_lstm<<<grid, BLK, 0, stream>>>(
        (const float*)d_in[0],  (const float*)d_in[1],  (const float*)d_in[2],
        (const float*)d_in[3],  (const float*)d_in[4],  (const float*)d_in[5],
        (const float*)d_in[6],  (const float*)d_in[7],  (const float*)d_in[8],
        (const float*)d_in[9],  (const float*)d_in[10], (const float*)d_in[11],
        (const float*)d_in[12], (const float*)d_in[13], (const float*)d_in[14],
        (const float*)d_in[15], (const float*)d_in[16], (const float*)d_in[17],
        (float*)d_out, B, T - 1, len_pred);
}

// Round 4
// 394.618 us; speedup vs baseline: 1.9711x; 1.9711x over previous
//
#include <hip/hip_runtime.h>
#include <math.h>

#define BLK 64
#define EPB 16            // elements per block (one wave)
#define NF 32

typedef __attribute__((ext_vector_type(8))) short s16x8;  // 8 bf16 = 4 VGPRs
typedef __attribute__((ext_vector_type(4))) float f32x4;

__device__ __forceinline__ float sigm(float x) {
    return __fdividef(1.0f, 1.0f + __expf(-x));
}
__device__ __forceinline__ float tanhft(float x) {
    float a = fabsf(x);
    float e = __expf(-2.0f * a);
    float t = __fdividef(1.0f - e, 1.0f + e);
    return copysignf(t, x);
}

__device__ __forceinline__ unsigned short bf16h(float x) {
    unsigned u = __float_as_uint(x);
    return (unsigned short)((u + 0x7FFFu + ((u >> 16) & 1u)) >> 16);
}
__device__ __forceinline__ float bf16tof(unsigned short h) {
    return __uint_as_float(((unsigned)h) << 16);
}
// split fp32 into hi+lo bf16 (~17-bit effective mantissa)
__device__ __forceinline__ void bsplit(float x, short& hi, short& lo) {
    unsigned short h = bf16h(x);
    hi = (short)h;
    lo = (short)bf16h(x - bf16tof(h));
}

// P = F P F^T for the constant-accel F (dt=0.2), in place
__device__ __forceinline__ void fpft(float (&P)[6][6]) {
    const float dt = 0.2f, hd = 0.02f;
    #pragma unroll
    for (int j = 0; j < 6; ++j) {
        float a0 = P[0][j] + dt * P[1][j] + hd * P[2][j];
        float a1 = P[1][j] + dt * P[2][j];
        float a3 = P[3][j] + dt * P[4][j] + hd * P[5][j];
        float a4 = P[4][j] + dt * P[5][j];
        P[0][j] = a0; P[1][j] = a1; P[3][j] = a3; P[4][j] = a4;
    }
    #pragma unroll
    for (int i = 0; i < 6; ++i) {
        float a0 = P[i][0] + dt * P[i][1] + hd * P[i][2];
        float a1 = P[i][1] + dt * P[i][2];
        float a3 = P[i][3] + dt * P[i][4] + hd * P[i][5];
        float a4 = P[i][4] + dt * P[i][5];
        P[i][0] = a0; P[i][1] = a1; P[i][3] = a3; P[i][4] = a4;
    }
}

#define GSTRIDE 21   // LDS gate buffer row stride (floats): <=2-way bank conflicts

// 1 wave/SIMD: 512 unified VGPR/AGPR budget -> weight frags (128) + state fit
// with ZERO scratch spill. 2048 waves run as 2 cohorts on 1024 SIMDs.
__global__ __launch_bounds__(BLK, 1)
void kalman_lstm(const float* __restrict__ hist,
                 const float* __restrict__ psx, const float* __restrict__ psy,
                 const float* __restrict__ vsx, const float* __restrict__ vsy,
                 const float* __restrict__ asx, const float* __restrict__ asy,
                 const float* __restrict__ jerk, const float* __restrict__ coefG,
                 const float* __restrict__ GRv,
                 const float* __restrict__ cfW, const float* __restrict__ cfb,
                 const float* __restrict__ Wih, const float* __restrict__ Whh,
                 const float* __restrict__ bih, const float* __restrict__ bhh,
                 const float* __restrict__ coW, const float* __restrict__ cob,
                 float* __restrict__ out, int B, int Thist, int len_pred)
{
    __shared__ float gbuf[128 * GSTRIDE];   // [gate 0..127][elem 0..15], stride 21

    const int lane = threadIdx.x;
    const int e = lane & 15;        // element slot within block
    const int s = lane >> 4;        // quad: k-slice / feature-slice owner
    const int b = blockIdx.x * EPB + e;

    const float dt = 0.2f;
    const float hd = 0.02f;
    const float g0 = dt * dt * dt / 6.0f;
    const float g1 = 0.02f;
    const float g2 = dt;

    // ---- uniform precompute ----
    float gr0 = GRv[0], gr1 = GRv[1];
    float R00 = gr0 * gr0, R01 = gr0 * gr1, R11 = gr1 * gr1;
    float ga0 = g0 * tanhf(coefG[0]);
    float ga1 = g1 * tanhf(coefG[1]);
    float ga2 = g2 * tanhf(coefG[2]);
    float gb3 = g0 * tanhf(coefG[3]);
    float gb4 = g1 * tanhf(coefG[4]);
    float gb5 = g2 * tanhf(coefG[5]);
    float j0 = jerk[0], j1 = jerk[1];

    // ---- LSTM weights once into register B-fragments (hi/lo bf16 split) ----
    s16x8 wih_h[8], wih_l[8], whh_h[8], whh_l[8];
    #pragma unroll
    for (int nt = 0; nt < 8; ++nt) {
        int row = nt * 16 + e;
        int base = row * NF + s * 8;
        #pragma unroll
        for (int j = 0; j < 8; ++j) {
            short hi, lo;
            bsplit(Wih[base + j], hi, lo);
            wih_h[nt][j] = hi; wih_l[nt][j] = lo;
            bsplit(Whh[base + j], hi, lo);
            whh_h[nt][j] = hi; whh_l[nt][j] = lo;
        }
    }
    float bias8[8];
    #pragma unroll
    for (int nt = 0; nt < 8; ++nt) {
        int g = nt * 16 + e;
        bias8[nt] = bih[g] + bhh[g];
    }

    // ---- Kalman init (replicated across the 4 lanes of each element) ----
    const float2* hist2 = (const float2*)hist;
    float2 z0 = hist2[b];
    float2 z1 = hist2[B + b];
    float X0 = z0.x, X1 = (z1.x - z0.x) / dt, X2 = 0.0f;
    float X3 = (z1.y - z0.y) / dt, X4 = 0.0f, X5 = 0.0f;  // ref overwrites slot 3

    float P[6][6];
    #pragma unroll
    for (int i = 0; i < 6; ++i)
        #pragma unroll
        for (int j = 0; j < 6; ++j) P[i][j] = 0.0f;
    { float v;
      v = psx[0]; P[0][0] = v * v;
      v = vsx[0]; P[1][1] = v * v;
      v = asx[0]; P[2][2] = v * v;
      v = psy[0]; P[3][3] = v * v;
      v = vsy[0]; P[4][4] = v * v;
      v = asy[0]; P[5][5] = v * v; }

    float creg[8];
    #pragma unroll
    for (int j = 0; j < 8; ++j) creg[j] = 0.0f;
    s16x8 ah_h = (s16x8)0, ah_l = (s16x8)0;   // h as A-fragment

    const int total = Thist + len_pred;
    for (int t = 0; t < total; ++t) {
        // ---- feat slice: f = 8s+jj, from current X ----
        s16x8 af_h, af_l;
        #pragma unroll
        for (int jj = 0; jj < 8; ++jj) {
            int f = 8 * s + jj;
            float acc = cfb[f]
                + cfW[f * 6 + 0] * X0 + cfW[f * 6 + 1] * X1 + cfW[f * 6 + 2] * X2
                + cfW[f * 6 + 3] * X3 + cfW[f * 6 + 4] * X4 + cfW[f * 6 + 5] * X5;
            float fv = tanhft(acc);
            short hi, lo; bsplit(fv, hi, lo);
            af_h[jj] = hi; af_l[jj] = lo;
        }

        __syncthreads();   // WAR on gbuf

        // ---- gates = [feat|h] @ W^T via MFMA (hi/lo split) ----
        #pragma unroll
        for (int nt = 0; nt < 8; ++nt) {
            f32x4 acc = {bias8[nt], bias8[nt], bias8[nt], bias8[nt]};
            acc = __builtin_amdgcn_mfma_f32_16x16x32_bf16(af_h, wih_h[nt], acc, 0, 0, 0);
            acc = __builtin_amdgcn_mfma_f32_16x16x32_bf16(af_l, wih_h[nt], acc, 0, 0, 0);
            acc = __builtin_amdgcn_mfma_f32_16x16x32_bf16(af_h, wih_l[nt], acc, 0, 0, 0);
            acc = __builtin_amdgcn_mfma_f32_16x16x32_bf16(ah_h, whh_h[nt], acc, 0, 0, 0);
            acc = __builtin_amdgcn_mfma_f32_16x16x32_bf16(ah_l, whh_h[nt], acc, 0, 0, 0);
            acc = __builtin_amdgcn_mfma_f32_16x16x32_bf16(ah_h, whh_l[nt], acc, 0, 0, 0);
            int wbase = (nt * 16 + e) * GSTRIDE + s * 4;
            gbuf[wbase + 0] = acc[0];
            gbuf[wbase + 1] = acc[1];
            gbuf[wbase + 2] = acc[2];
            gbuf[wbase + 3] = acc[3];
        }

        __syncthreads();   // RAW on gbuf

        // ---- combine: lane (e,s) handles features [8s,8s+8) of element e ----
        #pragma unroll
        for (int jj = 0; jj < 8; ++jj) {
            int f = 8 * s + jj;
            float gi = gbuf[(f)      * GSTRIDE + e];
            float gf = gbuf[(32 + f) * GSTRIDE + e];
            float gg = gbuf[(64 + f) * GSTRIDE + e];
            float go = gbuf[(96 + f) * GSTRIDE + e];
            float cn = sigm(gf) * creg[jj] + sigm(gi) * tanhft(gg);
            creg[jj] = cn;
            float hn = sigm(go) * tanhft(cn);
            short hi, lo; bsplit(hn, hi, lo);
            ah_h[jj] = hi; ah_l[jj] = lo;
        }

        if (t < Thist) {
            // ---------- history step: predict + measurement update ----------
            float2 z = hist2[(size_t)(t + 1) * B + b];
            X0 = X0 + dt * X1 + hd * X2;  X1 = X1 + dt * X2;
            X3 = X3 + dt * X4 + hd * X5;  X4 = X4 + dt * X5;
            fpft(P);
            {   // Q_hist = blockdiag(qa qa^T, qb qb^T)
                float qa[3] = {ga0 * j0, ga1 * j0, ga2 * j0};
                float qb[3] = {gb3 * j1, gb4 * j1, gb5 * j1};
                #pragma unroll
                for (int i = 0; i < 3; ++i)
                    #pragma unroll
                    for (int j = 0; j < 3; ++j) {
                        P[i][j]         += qa[i] * qa[j];
                        P[3 + i][3 + j] += qb[i] * qb[j];
                    }
            }
            float y0 = z.x - X0, y1 = z.y - X3;
            float S00 = P[0][0] + R00;
            float S01 = P[0][3] + R01;           // = S10 (P symmetric)
            float S11 = P[3][3] + R11;
            float idet = 1.0f / (S00 * S11 - S01 * S01);
            float i00 =  S11 * idet, i01 = -S01 * idet, i11 = S00 * idet;
            float K0[6], K1[6];
            #pragma unroll
            for (int i = 0; i < 6; ++i) {
                K0[i] = P[i][0] * i00 + P[i][3] * i01;
                K1[i] = P[i][0] * i01 + P[i][3] * i11;
            }
            X0 += K0[0] * y0 + K1[0] * y1;
            X1 += K0[1] * y0 + K1[1] * y1;
            X2 += K0[2] * y0 + K1[2] * y1;
            X3 += K0[3] * y0 + K1[3] * y1;
            X4 += K0[4] * y0 + K1[4] * y1;
            X5 += K0[5] * y0 + K1[5] * y1;
            // P' = (I-KH)P  (== Joseph exactly for optimal K), in place
            #pragma unroll
            for (int i = 0; i < 6; ++i) {
                P[i][1] -= K0[1] * P[i][0] + K1[1] * P[i][3];
                P[i][2] -= K0[2] * P[i][0] + K1[2] * P[i][3];
                P[i][4] -= K0[4] * P[i][0] + K1[4] * P[i][3];
                P[i][5] -= K0[5] * P[i][0] + K1[5] * P[i][3];
                float t0 = P[i][0] - (K0[0] * P[i][0] + K1[0] * P[i][3]);
                float t3 = P[i][3] - (K0[3] * P[i][0] + K1[3] * P[i][3]);
                P[i][0] = t0; P[i][3] = t3;
            }
        } else {
            // ---------- prediction step ----------
            float c0 = 0.0f, c1 = 0.0f, c2 = 0.0f, c3 = 0.0f;
            #pragma unroll
            for (int jj = 0; jj < 8; ++jj) {
                int f = 8 * s + jj;
                float hk = bf16tof((unsigned short)ah_h[jj])
                         + bf16tof((unsigned short)ah_l[jj]);
                c0 += coW[0 * NF + f] * hk;
                c1 += coW[1 * NF + f] * hk;
                c2 += coW[2 * NF + f] * hk;
                c3 += coW[3 * NF + f] * hk;
            }
            c0 += __shfl_xor(c0, 16, 64); c0 += __shfl_xor(c0, 32, 64);
            c1 += __shfl_xor(c1, 16, 64); c1 += __shfl_xor(c1, 32, 64);
            c2 += __shfl_xor(c2, 16, 64); c2 += __shfl_xor(c2, 32, 64);
            c3 += __shfl_xor(c3, 16, 64); c3 += __shfl_xor(c3, 32, 64);
            float cmd0 = c0 + cob[0], cmd1 = c1 + cob[1];
            float cmd2 = c2 + cob[2], cmd3 = c3 + cob[3];

            X0 = X0 + dt * X1 + hd * X2 + g0 * cmd0;
            X1 = X1 + dt * X2 + g1 * cmd0;
            X2 = X2 + g2 * cmd0;
            X3 = X3 + dt * X4 + hd * X5 + g0 * cmd1;
            X4 = X4 + dt * X5 + g1 * cmd1;
            X5 = X5 + g2 * cmd1;
            float Gs[6] = {ga0 * cmd2, ga1 * cmd2, ga2 * cmd2,
                           gb3 * cmd3, gb4 * cmd3, gb5 * cmd3};
            fpft(P);
            #pragma unroll
            for (int i = 0; i < 6; ++i)
                #pragma unroll
                for (int j = 0; j < 6; ++j)
                    P[i][j] += Gs[i] * Gs[j];

            int tp = t - Thist;
            float sx = sqrtf(P[0][0]), sy = sqrtf(P[3][3]);
            float rho = (P[0][3] + P[3][0]) / (2.0f * sx * sy);
            if (s == 0) {
                size_t o = ((size_t)tp * B + b) * 5u;
                out[o + 0] = X0;
                out[o + 1] = X3;
                out[o + 2] = sx;
                out[o + 3] = sy;
                out[o + 4] = rho;
            }
        }
    }
}

extern "C" void kernel_launch(void* const* d_in, const int* in_sizes, int n_in,
                              void* d_out, int out_size, void* d_ws, size_t ws_size,
                              hipStream_t stream) {
    const int T = 16;
    const int B = in_sizes[0] / (2 * T);      // 32768
    const int len_pred = out_size / (5 * B);  // 25
    const int grid = (B + EPB - 1) / EPB;     // one wave per 16 elements
    kalman_lstm<<<grid, BLK, 0, stream>>>(
        (const float*)d_in[0],  (const float*)d_in[1],  (const float*)d_in[2],
        (const float*)d_in[3],  (const float*)d_in[4],  (const float*)d_in[5],
        (const float*)d_in[6],  (const float*)d_in[7],  (const float*)d_in[8],
        (const float*)d_in[9],  (const float*)d_in[10], (const float*)d_in[11],
        (const float*)d_in[12], (const float*)d_in[13], (const float*)d_in[14],
        (const float*)d_in[15], (const float*)d_in[16], (const float*)d_in[17],
        (float*)d_out, B, T - 1, len_pred);
}

// Round 5
// 311.114 us; speedup vs baseline: 2.5002x; 1.2684x over previous
//
#include <hip/hip_runtime.h>
#include <math.h>

#define BLK 64
#define EPB 16            // elements per block (one wave)
#define NF 32
#define THIST 15

typedef __attribute__((ext_vector_type(8))) short s16x8;  // 8 bf16 = 4 VGPRs
typedef __attribute__((ext_vector_type(4))) float f32x4;

__device__ __forceinline__ float sigm(float x) {
    return __fdividef(1.0f, 1.0f + __expf(-x));
}
__device__ __forceinline__ float tanhft(float x) {
    float a = fabsf(x);
    float e = __expf(-2.0f * a);
    float t = __fdividef(1.0f - e, 1.0f + e);
    return copysignf(t, x);
}
__device__ __forceinline__ unsigned short bf16h(float x) {
    unsigned u = __float_as_uint(x);
    return (unsigned short)((u + 0x7FFFu + ((u >> 16) & 1u)) >> 16);
}
__device__ __forceinline__ float bf16tof(unsigned short h) {
    return __uint_as_float(((unsigned)h) << 16);
}
__device__ __forceinline__ void bsplit(float x, short& hi, short& lo) {
    unsigned short h = bf16h(x);
    hi = (short)h;
    lo = (short)bf16h(x - bf16tof(h));
}

// P = F P F^T for the constant-accel F (dt=0.2), in place
__device__ __forceinline__ void fpft(float (&P)[6][6]) {
    const float dt = 0.2f, hd = 0.02f;
    #pragma unroll
    for (int j = 0; j < 6; ++j) {
        float a0 = P[0][j] + dt * P[1][j] + hd * P[2][j];
        float a1 = P[1][j] + dt * P[2][j];
        float a3 = P[3][j] + dt * P[4][j] + hd * P[5][j];
        float a4 = P[4][j] + dt * P[5][j];
        P[0][j] = a0; P[1][j] = a1; P[3][j] = a3; P[4][j] = a4;
    }
    #pragma unroll
    for (int i = 0; i < 6; ++i) {
        float a0 = P[i][0] + dt * P[i][1] + hd * P[i][2];
        float a1 = P[i][1] + dt * P[i][2];
        float a3 = P[i][3] + dt * P[i][4] + hd * P[i][5];
        float a4 = P[i][4] + dt * P[i][5];
        P[i][0] = a0; P[i][1] = a1; P[i][3] = a3; P[i][4] = a4;
    }
}

// -------- pre-kernel: batch-uniform Kalman gains for the history phase --------
// ws layout: [t*12 .. t*12+5] = K0, [t*12+6 .. +11] = K1  (t = 0..14), [180..215] = P_final
__global__ void kf_precomp(const float* __restrict__ psx, const float* __restrict__ psy,
                           const float* __restrict__ vsx, const float* __restrict__ vsy,
                           const float* __restrict__ asx, const float* __restrict__ asy,
                           const float* __restrict__ jerk, const float* __restrict__ coefG,
                           const float* __restrict__ GRv, float* __restrict__ ws) {
    if (threadIdx.x != 0 || blockIdx.x != 0) return;
    const float dt = 0.2f, g0 = dt * dt * dt / 6.0f, g1 = 0.02f, g2 = dt;
    float gr0 = GRv[0], gr1 = GRv[1];
    float R00 = gr0 * gr0, R01 = gr0 * gr1, R11 = gr1 * gr1;
    float j0 = jerk[0], j1 = jerk[1];
    float qa[3] = {g0 * tanhf(coefG[0]) * j0, g1 * tanhf(coefG[1]) * j0, g2 * tanhf(coefG[2]) * j0};
    float qb[3] = {g0 * tanhf(coefG[3]) * j1, g1 * tanhf(coefG[4]) * j1, g2 * tanhf(coefG[5]) * j1};

    float P[6][6];
    for (int i = 0; i < 6; ++i)
        for (int j = 0; j < 6; ++j) P[i][j] = 0.0f;
    { float v;
      v = psx[0]; P[0][0] = v * v;
      v = vsx[0]; P[1][1] = v * v;
      v = asx[0]; P[2][2] = v * v;
      v = psy[0]; P[3][3] = v * v;
      v = vsy[0]; P[4][4] = v * v;
      v = asy[0]; P[5][5] = v * v; }

    for (int t = 0; t < THIST; ++t) {
        fpft(P);
        for (int i = 0; i < 3; ++i)
            for (int j = 0; j < 3; ++j) {
                P[i][j]         += qa[i] * qa[j];
                P[3 + i][3 + j] += qb[i] * qb[j];
            }
        float S00 = P[0][0] + R00;
        float S01 = P[0][3] + R01;
        float S11 = P[3][3] + R11;
        float idet = 1.0f / (S00 * S11 - S01 * S01);
        float i00 =  S11 * idet, i01 = -S01 * idet, i11 = S00 * idet;
        float K0[6], K1[6];
        for (int i = 0; i < 6; ++i) {
            K0[i] = P[i][0] * i00 + P[i][3] * i01;
            K1[i] = P[i][0] * i01 + P[i][3] * i11;
            ws[t * 12 + i]     = K0[i];
            ws[t * 12 + 6 + i] = K1[i];
        }
        for (int i = 0; i < 6; ++i) {
            P[i][1] -= K0[1] * P[i][0] + K1[1] * P[i][3];
            P[i][2] -= K0[2] * P[i][0] + K1[2] * P[i][3];
            P[i][4] -= K0[4] * P[i][0] + K1[4] * P[i][3];
            P[i][5] -= K0[5] * P[i][0] + K1[5] * P[i][3];
            float t0 = P[i][0] - (K0[0] * P[i][0] + K1[0] * P[i][3]);
            float t3 = P[i][3] - (K0[3] * P[i][0] + K1[3] * P[i][3]);
            P[i][0] = t0; P[i][3] = t3;
        }
    }
    for (int i = 0; i < 6; ++i)
        for (int j = 0; j < 6; ++j) ws[180 + i * 6 + j] = P[i][j];
}

// ------------------------------- main kernel ---------------------------------
__global__ __launch_bounds__(BLK, 2)
void kalman_lstm(const float* __restrict__ hist,
                 const float* __restrict__ coefG,
                 const float* __restrict__ cfW, const float* __restrict__ cfb,
                 const float* __restrict__ Wih, const float* __restrict__ Whh,
                 const float* __restrict__ bih, const float* __restrict__ bhh,
                 const float* __restrict__ coW, const float* __restrict__ cob,
                 const float* __restrict__ ws,
                 float* __restrict__ out, int B, int len_pred)
{
    __shared__ float biasL[128];          // gate biases bih+bhh
    __shared__ float coL[4 * NF];         // command weights
    __shared__ float cfwL[NF * 6];        // feature weights
    __shared__ float cfbL[NF];
    __shared__ unsigned hx[NF * 17];      // packed h exchange: [feat][elem], stride 17

    const int lane = threadIdx.x;
    const int e = lane & 15;              // element slot (MFMA B n-index / D col)
    const int s = lane >> 4;              // quad (k-slice / D row group)
    const int b = blockIdx.x * EPB + e;

    // ---- stash uniform tables in LDS ----
    biasL[lane]      = bih[lane]      + bhh[lane];
    biasL[lane + 64] = bih[lane + 64] + bhh[lane + 64];
    coL[lane]      = coW[lane];
    coL[lane + 64] = coW[lane + 64];
    for (int i = lane; i < NF * 6; i += BLK) cfwL[i] = cfW[i];
    if (lane < NF) cfbL[lane] = cfb[lane];

    const float dt = 0.2f, hd = 0.02f;
    const float g0 = dt * dt * dt / 6.0f, g1 = 0.02f, g2 = dt;
    float ga0 = g0 * tanhf(coefG[0]);
    float ga1 = g1 * tanhf(coefG[1]);
    float ga2 = g2 * tanhf(coefG[2]);
    float gb3 = g0 * tanhf(coefG[3]);
    float gb4 = g1 * tanhf(coefG[4]);
    float gb5 = g2 * tanhf(coefG[5]);

    // ---- LSTM weights once into register fragments (hi/lo bf16 split) ----
    // A-operand layout: lane holds W[(nt*16 + e)][s*8 + j]
    s16x8 wih_h[8], wih_l[8], whh_h[8], whh_l[8];
    #pragma unroll
    for (int nt = 0; nt < 8; ++nt) {
        int base = (nt * 16 + e) * NF + s * 8;
        #pragma unroll
        for (int j = 0; j < 8; ++j) {
            short hi, lo;
            bsplit(Wih[base + j], hi, lo);
            wih_h[nt][j] = hi; wih_l[nt][j] = lo;
            bsplit(Whh[base + j], hi, lo);
            whh_h[nt][j] = hi; whh_l[nt][j] = lo;
        }
    }

    // ---- Kalman state X (replicated across the 4 s-lanes of each element) ----
    const float2* hist2 = (const float2*)hist;
    float2 z0 = hist2[b];
    float2 z1 = hist2[B + b];
    float X0 = z0.x, X1 = (z1.x - z0.x) / dt, X2 = 0.0f;
    float X3 = (z1.y - z0.y) / dt, X4 = 0.0f, X5 = 0.0f;  // ref overwrites slot 3

    // LSTM state: lane (e,s) combines features {4s+r, 16+4s+r} of element e
    float creg[8], hn[8];
    #pragma unroll
    for (int j = 0; j < 8; ++j) { creg[j] = 0.0f; hn[j] = 0.0f; }
    s16x8 ah_h = (s16x8)0, ah_l = (s16x8)0;   // h as B-fragment (k=8s+j)

    __syncthreads();   // tables visible

    // One LSTM step: feat(X) -> gates (MFMA, W as A-operand) -> in-register
    // combine -> packed h exchange through LDS -> refresh ah fragments.
    auto lstm_step = [&]() {
        s16x8 af_h, af_l;
        #pragma unroll
        for (int jj = 0; jj < 8; ++jj) {
            int f = 8 * s + jj;
            float acc = cfbL[f]
                + cfwL[f * 6 + 0] * X0 + cfwL[f * 6 + 1] * X1 + cfwL[f * 6 + 2] * X2
                + cfwL[f * 6 + 3] * X3 + cfwL[f * 6 + 4] * X4 + cfwL[f * 6 + 5] * X5;
            float fv = tanhft(acc);
            short hi, lo; bsplit(fv, hi, lo);
            af_h[jj] = hi; af_l[jj] = lo;
        }

        __syncthreads();   // WAR: previous iteration's hx reads done

        // D[m=gate 4s+r of tile nt][n=elem e]  (bias preloaded as C)
        f32x4 acc[8];
        #pragma unroll
        for (int nt = 0; nt < 8; ++nt)
            acc[nt] = *(const f32x4*)&biasL[nt * 16 + 4 * s];
        #pragma unroll
        for (int nt = 0; nt < 8; ++nt) {
            acc[nt] = __builtin_amdgcn_mfma_f32_16x16x32_bf16(wih_h[nt], af_h, acc[nt], 0, 0, 0);
            acc[nt] = __builtin_amdgcn_mfma_f32_16x16x32_bf16(wih_h[nt], af_l, acc[nt], 0, 0, 0);
            acc[nt] = __builtin_amdgcn_mfma_f32_16x16x32_bf16(wih_l[nt], af_h, acc[nt], 0, 0, 0);
            acc[nt] = __builtin_amdgcn_mfma_f32_16x16x32_bf16(whh_h[nt], ah_h, acc[nt], 0, 0, 0);
            acc[nt] = __builtin_amdgcn_mfma_f32_16x16x32_bf16(whh_h[nt], ah_l, acc[nt], 0, 0, 0);
            acc[nt] = __builtin_amdgcn_mfma_f32_16x16x32_bf16(whh_l[nt], ah_h, acc[nt], 0, 0, 0);
        }

        // in-register combine: gate tiles {0,1}=i, {2,3}=f, {4,5}=g, {6,7}=o;
        // tile parity = feature block. Lane's feature f = 16*blk + 4*s + r.
        #pragma unroll
        for (int blk = 0; blk < 2; ++blk) {
            #pragma unroll
            for (int r = 0; r < 4; ++r) {
                float gi = acc[0 + blk][r];
                float gf = acc[2 + blk][r];
                float gg = acc[4 + blk][r];
                float go = acc[6 + blk][r];
                float cn = sigm(gf) * creg[4 * blk + r] + sigm(gi) * tanhft(gg);
                creg[4 * blk + r] = cn;
                float hv = sigm(go) * tanhft(cn);
                hn[4 * blk + r] = hv;
                short hi, lo; bsplit(hv, hi, lo);
                hx[(16 * blk + 4 * s + r) * 17 + e] =
                    (unsigned)(unsigned short)hi | ((unsigned)(unsigned short)lo << 16);
            }
        }

        __syncthreads();   // RAW: exchanged h visible

        #pragma unroll
        for (int j = 0; j < 8; ++j) {
            unsigned v = hx[(8 * s + j) * 17 + e];
            ah_h[j] = (short)(v & 0xffffu);
            ah_l[j] = (short)(v >> 16);
        }
    };

    // ---------------- history phase: X-only update, uniform K from ws ----------------
    #pragma unroll 1
    for (int t = 0; t < THIST; ++t) {
        lstm_step();
        float2 z = hist2[(size_t)(t + 1) * B + b];
        const float* kp = ws + t * 12;            // wave-uniform -> s_load
        X0 = X0 + dt * X1 + hd * X2;  X1 = X1 + dt * X2;
        X3 = X3 + dt * X4 + hd * X5;  X4 = X4 + dt * X5;
        float y0 = z.x - X0, y1 = z.y - X3;
        X0 += kp[0] * y0 + kp[6]  * y1;
        X1 += kp[1] * y0 + kp[7]  * y1;
        X2 += kp[2] * y0 + kp[8]  * y1;
        X3 += kp[3] * y0 + kp[9]  * y1;
        X4 += kp[4] * y0 + kp[10] * y1;
        X5 += kp[5] * y0 + kp[11] * y1;
    }

    // P becomes data-dependent only now; init from uniform post-history P
    float P[6][6];
    #pragma unroll
    for (int i = 0; i < 6; ++i)
        #pragma unroll
        for (int j = 0; j < 6; ++j) P[i][j] = ws[180 + i * 6 + j];

    // ---------------- prediction phase ----------------
    #pragma unroll 1
    for (int tp = 0; tp < len_pred; ++tp) {
        lstm_step();
        // command = coW @ h + cob, partial over lane's 8 features, reduce over s
        float c0 = 0.0f, c1 = 0.0f, c2 = 0.0f, c3 = 0.0f;
        #pragma unroll
        for (int blk = 0; blk < 2; ++blk)
            #pragma unroll
            for (int r = 0; r < 4; ++r) {
                int f = 16 * blk + 4 * s + r;
                float hk = hn[4 * blk + r];
                c0 += coL[0 * NF + f] * hk;
                c1 += coL[1 * NF + f] * hk;
                c2 += coL[2 * NF + f] * hk;
                c3 += coL[3 * NF + f] * hk;
            }
        c0 += __shfl_xor(c0, 16, 64); c0 += __shfl_xor(c0, 32, 64);
        c1 += __shfl_xor(c1, 16, 64); c1 += __shfl_xor(c1, 32, 64);
        c2 += __shfl_xor(c2, 16, 64); c2 += __shfl_xor(c2, 32, 64);
        c3 += __shfl_xor(c3, 16, 64); c3 += __shfl_xor(c3, 32, 64);
        float cmd0 = c0 + cob[0], cmd1 = c1 + cob[1];
        float cmd2 = c2 + cob[2], cmd3 = c3 + cob[3];

        X0 = X0 + dt * X1 + hd * X2 + g0 * cmd0;
        X1 = X1 + dt * X2 + g1 * cmd0;
        X2 = X2 + g2 * cmd0;
        X3 = X3 + dt * X4 + hd * X5 + g0 * cmd1;
        X4 = X4 + dt * X5 + g1 * cmd1;
        X5 = X5 + g2 * cmd1;
        float Gs[6] = {ga0 * cmd2, ga1 * cmd2, ga2 * cmd2,
                       gb3 * cmd3, gb4 * cmd3, gb5 * cmd3};
        fpft(P);
        #pragma unroll
        for (int i = 0; i < 6; ++i)
            #pragma unroll
            for (int j = 0; j < 6; ++j)
                P[i][j] += Gs[i] * Gs[j];

        float sx = sqrtf(P[0][0]), sy = sqrtf(P[3][3]);
        float rho = (P[0][3] + P[3][0]) / (2.0f * sx * sy);
        if (s == 0) {
            size_t o = ((size_t)tp * B + b) * 5u;
            out[o + 0] = X0;
            out[o + 1] = X3;
            out[o + 2] = sx;
            out[o + 3] = sy;
            out[o + 4] = rho;
        }
    }
}

extern "C" void kernel_launch(void* const* d_in, const int* in_sizes, int n_in,
                              void* d_out, int out_size, void* d_ws, size_t ws_size,
                              hipStream_t stream) {
    const int T = 16;
    const int B = in_sizes[0] / (2 * T);      // 32768
    const int len_pred = out_size / (5 * B);  // 25
    float* ws = (float*)d_ws;

    kf_precomp<<<1, 64, 0, stream>>>(
        (const float*)d_in[1], (const float*)d_in[2], (const float*)d_in[3],
        (const float*)d_in[4], (const float*)d_in[5], (const float*)d_in[6],
        (const float*)d_in[7], (const float*)d_in[8], (const float*)d_in[9], ws);

    const int grid = (B + EPB - 1) / EPB;     // one wave per 16 elements
    kalman_lstm<<<grid, BLK, 0, stream>>>(
        (const float*)d_in[0],  (const float*)d_in[8],
        (const float*)d_in[10], (const float*)d_in[11],
        (const float*)d_in[12], (const float*)d_in[13], (const float*)d_in[14],
        (const float*)d_in[15], (const float*)d_in[16], (const float*)d_in[17],
        ws, (float*)d_out, B, len_pred);
}